// Round 1
// baseline (1758.568 us; speedup 1.0000x reference)
//
#include <hip/hip_runtime.h>
#include <stdint.h>

#define NN 50000
#define NE 800000
#define DN 128
#define DE 64
#define NG 512
#define HD 256
#define LDA 72  // padded LDS stride (elems) for 64-elem rows

typedef unsigned short ushort_t;
typedef __attribute__((ext_vector_type(8))) short short8;
typedef __attribute__((ext_vector_type(4))) float floatx4;

__device__ __forceinline__ float bf2f(ushort_t h){ unsigned u=((unsigned)h)<<16; float f; __builtin_memcpy(&f,&u,4); return f; }
__device__ __forceinline__ ushort_t f2bf(float f){ unsigned u; __builtin_memcpy(&u,&f,4); u += 0x7FFFu + ((u>>16)&1u); return (ushort_t)(u>>16); }
__device__ __forceinline__ unsigned pk2(float a,float b){ return (unsigned)f2bf(a) | ((unsigned)f2bf(b)<<16); }

// ---------------- weight conversion ----------------
__global__ void k_conv_node_w(const float* Wf, const float* Ws, ushort_t* out){
  int i = blockIdx.x*256 + threadIdx.x;
  if(i >= 2*512*128) return;
  int l = i >> 16;
  int r = i & 65535;
  int n = r >> 7, k = r & 127;
  const float* W = (n<256)? Wf : Ws;
  int nn = n & 127;
  int koff = ((n>>7)&1) ? 128+k : k;
  out[i] = f2bf(W[(size_t)l*128*320 + (size_t)nn*320 + koff]);
}

__global__ void k_conv_edge_w(const float* Wf, const float* Ws, ushort_t* out){
  int i = blockIdx.x*256 + threadIdx.x;
  if(i >= 2*256*64) return;
  int l = i >> 14;
  int r = i & 16383;
  int n = r >> 6, k = r & 63;
  const float* W = (n<128)? Wf : Ws;
  int nn = n & 127;
  out[i] = f2bf(W[(size_t)l*128*320 + (size_t)nn*320 + 256 + k]);
}

__global__ void k_f2bf(const float* s, ushort_t* d, int n){
  int i = blockIdx.x*256 + threadIdx.x;
  if(i<n) d[i] = f2bf(s[i]);
}

__global__ void k_init_x(const float* x, float* xcur, ushort_t* xb){
  int i = blockIdx.x*256 + threadIdx.x;
  if(i < NN*DN){ float v = x[i]; xcur[i]=v; xb[i]=f2bf(v); }
}

__global__ void k_zero_u32(unsigned* p, int n){
  int i = blockIdx.x*256 + threadIdx.x;
  if(i<n) p[i]=0u;
}

// ---------------- CSR build ----------------
__global__ void k_hist(const int* dst, int* deg){
  int i = blockIdx.x*256 + threadIdx.x;
  if(i<NE) atomicAdd(&deg[dst[i]], 1);
}

__global__ void k_blocksum(const int* deg, int* bsum, int n){
  __shared__ int s[256];
  int t = threadIdx.x, i = blockIdx.x*256 + t;
  s[t] = (i<n)? deg[i] : 0;
  __syncthreads();
  for(int o=128;o>0;o>>=1){ if(t<o) s[t]+=s[t+o]; __syncthreads(); }
  if(t==0) bsum[blockIdx.x]=s[0];
}

__global__ void k_scan_bsum(int* bsum, int nb, int* offs, int nnodes){
  __shared__ int s[2][256];
  int t = threadIdx.x;
  int v = (t<nb)? bsum[t] : 0;
  s[0][t]=v; __syncthreads();
  int cur=0;
  for(int o=1;o<256;o<<=1){
    int nx=cur^1;
    s[nx][t] = s[cur][t] + ((t>=o)? s[cur][t-o] : 0);
    cur=nx; __syncthreads();
  }
  if(t<nb) bsum[t] = s[cur][t] - v;      // exclusive
  if(t==255) offs[nnodes] = s[cur][255]; // total
}

__global__ void k_scanscatter(const int* deg, const int* bsum, int* offs, int* cursor, int n){
  __shared__ int s[2][256];
  int t=threadIdx.x, i=blockIdx.x*256+t;
  int v=(i<n)? deg[i] : 0;
  s[0][t]=v; __syncthreads();
  int cur=0;
  for(int o=1;o<256;o<<=1){
    int nx=cur^1;
    s[nx][t] = s[cur][t] + ((t>=o)? s[cur][t-o] : 0);
    cur=nx; __syncthreads();
  }
  if(i<n){ int ex = s[cur][t]-v + bsum[blockIdx.x]; offs[i]=ex; cursor[i]=ex; }
}

__global__ void k_scatter(const int* dst, int* cursor, int* eid){
  int i = blockIdx.x*256 + threadIdx.x;
  if(i<NE){ int pos = atomicAdd(&cursor[dst[i]], 1); eid[pos]=i; }
}

// ---------------- generic bf16 MFMA GEMM ----------------
__global__ __launch_bounds__(256) void k_gemm(const ushort_t* __restrict__ Ain, const ushort_t* __restrict__ Wg,
      int M, int N, int K, const float* __restrict__ bias, int mode,
      ushort_t* __restrict__ outb, float* __restrict__ outf, const float* __restrict__ addf){
  __shared__ __align__(16) ushort_t As[64*LDA];
  __shared__ __align__(16) ushort_t Bs[64*LDA];
  int tid = threadIdx.x;
  int m0 = blockIdx.x*64, n0 = blockIdx.y*64;
  int w = tid>>6, lane = tid&63, row16 = lane&15, quad = lane>>4;
  floatx4 acc[4];
  #pragma unroll
  for(int t=0;t<4;t++) acc[t]=(floatx4)(0.f);
  int nk = K>>6;
  for(int kc=0; kc<nk; kc++){
    #pragma unroll
    for(int i=0;i<2;i++){
      int lin = tid + i*256;
      int row = lin>>3, c8 = (lin&7)*8;
      uint4 va;
      int gm = m0+row;
      if(gm < M) va = *(const uint4*)&Ain[(size_t)gm*K + kc*64 + c8];
      else va = make_uint4(0,0,0,0);
      *(uint4*)&As[row*LDA + c8] = va;
      uint4 vb = *(const uint4*)&Wg[(size_t)(n0+row)*K + kc*64 + c8];
      *(uint4*)&Bs[row*LDA + c8] = vb;
    }
    __syncthreads();
    #pragma unroll
    for(int ks=0;ks<2;ks++){
      short8 a = *(const short8*)&As[(w*16+row16)*LDA + ks*32 + quad*8];
      #pragma unroll
      for(int t=0;t<4;t++){
        short8 b = *(const short8*)&Bs[(t*16+row16)*LDA + ks*32 + quad*8];
        acc[t] = __builtin_amdgcn_mfma_f32_16x16x32_bf16(a,b,acc[t],0,0,0);
      }
    }
    __syncthreads();
  }
  #pragma unroll
  for(int t=0;t<4;t++){
    int nn = n0 + t*16 + row16;
    #pragma unroll
    for(int r=0;r<4;r++){
      int m = m0 + w*16 + quad*4 + r;
      if(m>=M) continue;
      float v = acc[t][r];
      if(mode==1){ v += bias[nn]; v = v>0.f? v:0.f; outb[(size_t)m*N+nn]=f2bf(v); }
      else if(mode==2){ v += bias[nn] + addf[(size_t)m*N+nn]; outf[(size_t)m*N+nn]=v; }
      else { outb[(size_t)m*N+nn]=f2bf(v); }
    }
  }
}

// ---------------- fused per-edge message kernel ----------------
__global__ __launch_bounds__(256) void k_edge_msg(const float* __restrict__ ea,
      const int* __restrict__ src_g, const int* __restrict__ dst_g,
      const ushort_t* __restrict__ Wedge, const ushort_t* __restrict__ Atab,
      const float* __restrict__ bf, const float* __restrict__ bs,
      ushort_t* __restrict__ msg){
  __shared__ __align__(16) ushort_t We[256*LDA];
  __shared__ __align__(16) ushort_t el[64*LDA];
  __shared__ int dl[64], sl[64];
  __shared__ float bfl[128], bsl[128];
  int tid = threadIdx.x;
  int e0 = blockIdx.x*64;
  {
    const uint4* s = (const uint4*)Wedge;
    #pragma unroll
    for(int i=0;i<8;i++){
      int idx = tid + i*256;
      int row = idx>>3, col = (idx&7)*8;
      *(uint4*)&We[row*LDA + col] = s[idx];
    }
  }
  {
    int row = tid>>2, c0 = (tid&3)*16;
    const float4* p = (const float4*)&ea[(size_t)(e0+row)*64 + c0];
    float4 f0=p[0], f1=p[1], f2=p[2], f3=p[3];
    uint4 q0, q1;
    q0.x=pk2(f0.x,f0.y); q0.y=pk2(f0.z,f0.w); q0.z=pk2(f1.x,f1.y); q0.w=pk2(f1.z,f1.w);
    q1.x=pk2(f2.x,f2.y); q1.y=pk2(f2.z,f2.w); q1.z=pk2(f3.x,f3.y); q1.w=pk2(f3.z,f3.w);
    *(uint4*)&el[row*LDA + c0] = q0;
    *(uint4*)&el[row*LDA + c0 + 8] = q1;
  }
  if(tid<64){ dl[tid]=dst_g[e0+tid]; sl[tid]=src_g[e0+tid]; }
  if(tid<128) bfl[tid]=bf[tid]; else bsl[tid-128]=bs[tid-128];
  __syncthreads();
  int w = tid>>6, lane = tid&63, row16 = lane&15, quad = lane>>4;
  floatx4 acc[16];
  #pragma unroll
  for(int t=0;t<16;t++) acc[t]=(floatx4)(0.f);
  #pragma unroll
  for(int ks=0;ks<2;ks++){
    short8 a = *(const short8*)&el[(w*16+row16)*LDA + ks*32 + quad*8];
    #pragma unroll
    for(int t=0;t<16;t++){
      short8 b = *(const short8*)&We[(t*16+row16)*LDA + ks*32 + quad*8];
      acc[t]=__builtin_amdgcn_mfma_f32_16x16x32_bf16(a,b,acc[t],0,0,0);
    }
  }
  #pragma unroll
  for(int t=0;t<8;t++){
    int c = t*16 + row16;
    float bfc = bfl[c], bsc = bsl[c];
    #pragma unroll
    for(int r=0;r<4;r++){
      int rl = w*16 + quad*4 + r;
      int e  = e0 + rl;
      int d  = dl[rl], s = sl[rl];
      const ushort_t* Ad  = Atab + (size_t)d*512;
      const ushort_t* Asr = Atab + (size_t)s*512;
      float fv = acc[t][r]   + bfc + bf2f(Ad[c])     + bf2f(Asr[128+c]);
      float sv = acc[t+8][r] + bsc + bf2f(Ad[256+c]) + bf2f(Asr[384+c]);
      float sig = 1.f/(1.f+__expf(-fv));
      float sp  = (sv>20.f)? sv : log1pf(__expf(sv));
      msg[(size_t)e*128 + c] = f2bf(sig*sp);
    }
  }
}

// ---------------- CSR aggregate ----------------
__global__ __launch_bounds__(256) void k_aggregate(const ushort_t* __restrict__ msg,
      const int* __restrict__ eid, const int* __restrict__ offs,
      float* __restrict__ xcur, ushort_t* __restrict__ xb){
  int v = blockIdx.x*4 + (threadIdx.x>>6);
  int lane = threadIdx.x & 63;
  int c0 = lane*2;
  float2 a = *(float2*)&xcur[(size_t)v*128 + c0];
  int b = offs[v], e_ = offs[v+1];
  for(int j=b;j<e_;j++){
    int e = eid[j];
    unsigned mm = *(const unsigned*)&msg[(size_t)e*128 + c0];
    a.x += bf2f((ushort_t)(mm & 0xffffu));
    a.y += bf2f((ushort_t)(mm >> 16));
  }
  *(float2*)&xcur[(size_t)v*128 + c0] = a;
  *(unsigned*)&xb[(size_t)v*128 + c0] = pk2(a.x, a.y);
}

// ---------------- pooling ----------------
__global__ void k_pool(const float* __restrict__ xcur, const int* __restrict__ batch, float* __restrict__ pooled){
  int i = blockIdx.x*256 + threadIdx.x;
  if(i >= NN*DN) return;
  int v = i>>7, c = i&127;
  atomicAdd(&pooled[(size_t)batch[v]*128 + c], xcur[i]);
}

// ---------------- mlp2 + residual + head ----------------
__global__ __launch_bounds__(256) void k_final(const float* __restrict__ pooled,
   const float* __restrict__ W0, const float* __restrict__ b0,
   const float* __restrict__ W1, const float* __restrict__ b1,
   const float* __restrict__ Wp, const float* __restrict__ bp,
   const float* __restrict__ outW, const float* __restrict__ outB,
   float* __restrict__ out){
  __shared__ float p[128], h0[256], h1[256], red[256];
  int g = blockIdx.x, t = threadIdx.x;
  if(t<128) p[t]=pooled[(size_t)g*128+t];
  __syncthreads();
  {
    const float4* wr = (const float4*)&W0[(size_t)t*128];
    float s=0.f;
    #pragma unroll 8
    for(int k=0;k<32;k++){ float4 wv=wr[k]; s += wv.x*p[k*4]+wv.y*p[k*4+1]+wv.z*p[k*4+2]+wv.w*p[k*4+3]; }
    s += b0[t]; h0[t] = s>0.f? s:0.f;
  }
  __syncthreads();
  {
    const float4* wr = (const float4*)&W1[(size_t)t*256];
    float s=0.f;
    #pragma unroll 8
    for(int k=0;k<64;k++){ float4 wv=wr[k]; s += wv.x*h0[k*4]+wv.y*h0[k*4+1]+wv.z*h0[k*4+2]+wv.w*h0[k*4+3]; }
    s += b1[t]; h1[t] = s>0.f? s:0.f;
  }
  __syncthreads();
  float rt = 0.f;
  if(t<128){
    const float4* wr=(const float4*)&Wp[(size_t)t*256];
    float s=0.f;
    #pragma unroll 8
    for(int k=0;k<64;k++){ float4 wv=wr[k]; s += wv.x*h1[k*4]+wv.y*h1[k*4+1]+wv.z*h1[k*4+2]+wv.w*h1[k*4+3]; }
    s += bp[t] + p[t];
    rt = s * outW[t];
  }
  red[t]=rt; __syncthreads();
  for(int o=128;o>0;o>>=1){ if(t<o) red[t]+=red[t+o]; __syncthreads(); }
  if(t==0) out[g] = red[0] + outB[0];
}

extern "C" void kernel_launch(void* const* d_in, const int* in_sizes, int n_in,
                              void* d_out, int out_size, void* d_ws, size_t ws_size,
                              hipStream_t stream){
  const float* x    = (const float*)d_in[0];
  const int*   ei   = (const int*)d_in[1];
  const float* ea   = (const float*)d_in[2];
  const int*   batch= (const int*)d_in[3];
  const float* cWf  = (const float*)d_in[4];
  const float* cbf  = (const float*)d_in[5];
  const float* cWs  = (const float*)d_in[6];
  const float* cbs  = (const float*)d_in[7];
  const float* W0   = (const float*)d_in[8];
  const float* b0   = (const float*)d_in[9];
  const float* W1   = (const float*)d_in[10];
  const float* b1   = (const float*)d_in[11];
  const float* Wp   = (const float*)d_in[12];
  const float* bp   = (const float*)d_in[13];
  const float* m2W0 = (const float*)d_in[14];
  const float* m2b0 = (const float*)d_in[15];
  const float* m2W1 = (const float*)d_in[16];
  const float* m2b1 = (const float*)d_in[17];
  const float* m2Wp = (const float*)d_in[18];
  const float* m2bp = (const float*)d_in[19];
  const float* outW = (const float*)d_in[20];
  const float* outB = (const float*)d_in[21];

  const int* srcp = ei;
  const int* dstp = ei + NE;

  char* ws = (char*)d_ws;
  size_t off = 0;
  auto alloc = [&](size_t bytes)->char*{
    char* p = ws + off;
    off += (bytes + 255) & ~(size_t)255;
    return p;
  };
  float*    xcur  = (float*)   alloc((size_t)NN*DN*4);
  ushort_t* xb    = (ushort_t*)alloc((size_t)NN*DN*2);
  ushort_t* Atab  = (ushort_t*)alloc((size_t)NN*512*2);   // reused as h0/h1 for mlp1
  ushort_t* msg   = (ushort_t*)alloc((size_t)NE*128*2);
  ushort_t* Wnode = (ushort_t*)alloc((size_t)2*512*128*2);
  ushort_t* Wedge = (ushort_t*)alloc((size_t)2*256*64*2);
  ushort_t* W0b   = (ushort_t*)alloc((size_t)256*128*2);
  ushort_t* W1b   = (ushort_t*)alloc((size_t)256*256*2);
  ushort_t* Wpb   = (ushort_t*)alloc((size_t)128*256*2);
  int*      deg   = (int*)     alloc((size_t)NN*4);
  int*      offs  = (int*)     alloc((size_t)(NN+1)*4);
  int*      cursor= (int*)     alloc((size_t)NN*4);
  int*      eid   = (int*)     alloc((size_t)NE*4);
  int*      bsum  = (int*)     alloc(256*4);
  float*    pooled= (float*)   alloc((size_t)NG*DN*4);
  ushort_t* h0 = Atab;
  ushort_t* h1 = Atab + (size_t)NN*256;

  k_conv_node_w<<<(2*512*128+255)/256, 256, 0, stream>>>(cWf, cWs, Wnode);
  k_conv_edge_w<<<(2*256*64+255)/256, 256, 0, stream>>>(cWf, cWs, Wedge);
  k_f2bf<<<(256*128+255)/256, 256, 0, stream>>>(W0, W0b, 256*128);
  k_f2bf<<<(256*256+255)/256, 256, 0, stream>>>(W1, W1b, 256*256);
  k_f2bf<<<(128*256+255)/256, 256, 0, stream>>>(Wp, Wpb, 128*256);
  k_init_x<<<(NN*DN+255)/256, 256, 0, stream>>>(x, xcur, xb);

  int nb = (NN+255)/256;
  k_zero_u32<<<(NN+255)/256, 256, 0, stream>>>((unsigned*)deg, NN);
  k_hist<<<(NE+255)/256, 256, 0, stream>>>(dstp, deg);
  k_blocksum<<<nb, 256, 0, stream>>>(deg, bsum, NN);
  k_scan_bsum<<<1, 256, 0, stream>>>(bsum, nb, offs, NN);
  k_scanscatter<<<nb, 256, 0, stream>>>(deg, bsum, offs, cursor, NN);
  k_scatter<<<(NE+255)/256, 256, 0, stream>>>(dstp, cursor, eid);

  for(int l=0;l<2;l++){
    dim3 ga((NN+63)/64, 512/64);
    k_gemm<<<ga, 256, 0, stream>>>(xb, Wnode + (size_t)l*512*128, NN, 512, 128,
                                   nullptr, 0, Atab, nullptr, nullptr);
    k_edge_msg<<<NE/64, 256, 0, stream>>>(ea, srcp, dstp, Wedge + (size_t)l*256*64,
                                          Atab, cbf + l*128, cbs + l*128, msg);
    k_aggregate<<<NN/4, 256, 0, stream>>>(msg, eid, offs, xcur, xb);
  }

  {
    dim3 g0((NN+63)/64, 256/64);
    k_gemm<<<g0, 256, 0, stream>>>(xb, W0b, NN, 256, 128, b0, 1, h0, nullptr, nullptr);
    dim3 g1((NN+63)/64, 256/64);
    k_gemm<<<g1, 256, 0, stream>>>(h0, W1b, NN, 256, 256, b1, 1, h1, nullptr, nullptr);
    dim3 g2((NN+63)/64, 128/64);
    k_gemm<<<g2, 256, 0, stream>>>(h1, Wpb, NN, 128, 256, bp, 2, nullptr, xcur, xcur);
  }

  k_zero_u32<<<(NG*DN+255)/256, 256, 0, stream>>>((unsigned*)pooled, NG*DN);
  k_pool<<<(NN*DN+255)/256, 256, 0, stream>>>(xcur, batch, pooled);

  k_final<<<NG, 256, 0, stream>>>(pooled, m2W0, m2b0, m2W1, m2b1, m2Wp, m2bp,
                                  outW, outB, (float*)d_out);
  (void)in_sizes; (void)n_in; (void)out_size; (void)ws_size;
}

// Round 2
// 1224.201 us; speedup vs baseline: 1.4365x; 1.4365x over previous
//
#include <hip/hip_runtime.h>
#include <stdint.h>

#define NN 50000
#define NE 800000
#define DN 128
#define DE 64
#define NG 512
#define HD 256
#define LDA 72   // padded LDS stride (elems) for 64-elem bf16 rows
#define SPK_S 132 // uint stride for packed fv/sv rows (528B, 16B-aligned)

typedef unsigned short ushort_t;
typedef __attribute__((ext_vector_type(8))) short short8;
typedef __attribute__((ext_vector_type(4))) float floatx4;

__device__ __forceinline__ float bf2f(ushort_t h){ unsigned u=((unsigned)h)<<16; float f; __builtin_memcpy(&f,&u,4); return f; }
__device__ __forceinline__ float bflo(unsigned u){ unsigned v=u<<16; float f; __builtin_memcpy(&f,&v,4); return f; }
__device__ __forceinline__ float bfhi(unsigned u){ unsigned v=u&0xffff0000u; float f; __builtin_memcpy(&f,&v,4); return f; }
__device__ __forceinline__ ushort_t f2bf(float f){ unsigned u; __builtin_memcpy(&u,&f,4); u += 0x7FFFu + ((u>>16)&1u); return (ushort_t)(u>>16); }
__device__ __forceinline__ unsigned pk2(float a,float b){ return (unsigned)f2bf(a) | ((unsigned)f2bf(b)<<16); }

// ---------------- weight conversion ----------------
__global__ void k_conv_node_w(const float* Wf, const float* Ws, ushort_t* out){
  int i = blockIdx.x*256 + threadIdx.x;
  if(i >= 2*512*128) return;
  int l = i >> 16;
  int r = i & 65535;
  int n = r >> 7, k = r & 127;
  const float* W = (n<256)? Wf : Ws;
  int nn = n & 127;
  int koff = ((n>>7)&1) ? 128+k : k;
  out[i] = f2bf(W[(size_t)l*128*320 + (size_t)nn*320 + koff]);
}

__global__ void k_conv_edge_w(const float* Wf, const float* Ws, ushort_t* out){
  int i = blockIdx.x*256 + threadIdx.x;
  if(i >= 2*256*64) return;
  int l = i >> 14;
  int r = i & 16383;
  int n = r >> 6, k = r & 63;
  const float* W = (n<128)? Wf : Ws;
  int nn = n & 127;
  out[i] = f2bf(W[(size_t)l*128*320 + (size_t)nn*320 + 256 + k]);
}

__global__ void k_f2bf(const float* s, ushort_t* d, int n){
  int i = blockIdx.x*256 + threadIdx.x;
  if(i<n) d[i] = f2bf(s[i]);
}

__global__ void k_init_x(const float* x, float* xcur, ushort_t* xb){
  int i = blockIdx.x*256 + threadIdx.x;
  if(i < NN*DN){ float v = x[i]; xcur[i]=v; xb[i]=f2bf(v); }
}

__global__ void k_zero_u32(unsigned* p, int n){
  int i = blockIdx.x*256 + threadIdx.x;
  if(i<n) p[i]=0u;
}

// ---------------- CSR build ----------------
__global__ void k_hist(const int* dst, int* deg){
  int i = blockIdx.x*256 + threadIdx.x;
  if(i<NE) atomicAdd(&deg[dst[i]], 1);
}

__global__ void k_blocksum(const int* deg, int* bsum, int n){
  __shared__ int s[256];
  int t = threadIdx.x, i = blockIdx.x*256 + t;
  s[t] = (i<n)? deg[i] : 0;
  __syncthreads();
  for(int o=128;o>0;o>>=1){ if(t<o) s[t]+=s[t+o]; __syncthreads(); }
  if(t==0) bsum[blockIdx.x]=s[0];
}

__global__ void k_scan_bsum(int* bsum, int nb, int* offs, int nnodes){
  __shared__ int s[2][256];
  int t = threadIdx.x;
  int v = (t<nb)? bsum[t] : 0;
  s[0][t]=v; __syncthreads();
  int cur=0;
  for(int o=1;o<256;o<<=1){
    int nx=cur^1;
    s[nx][t] = s[cur][t] + ((t>=o)? s[cur][t-o] : 0);
    cur=nx; __syncthreads();
  }
  if(t<nb) bsum[t] = s[cur][t] - v;      // exclusive
  if(t==255) offs[nnodes] = s[cur][255]; // total
}

__global__ void k_scanscatter(const int* deg, const int* bsum, int* offs, int* cursor, int n){
  __shared__ int s[2][256];
  int t=threadIdx.x, i=blockIdx.x*256+t;
  int v=(i<n)? deg[i] : 0;
  s[0][t]=v; __syncthreads();
  int cur=0;
  for(int o=1;o<256;o<<=1){
    int nx=cur^1;
    s[nx][t] = s[cur][t] + ((t>=o)? s[cur][t-o] : 0);
    cur=nx; __syncthreads();
  }
  if(i<n){ int ex = s[cur][t]-v + bsum[blockIdx.x]; offs[i]=ex; cursor[i]=ex; }
}

__global__ void k_scatter(const int* dst, int* cursor, int* eid){
  int i = blockIdx.x*256 + threadIdx.x;
  if(i<NE){ int pos = atomicAdd(&cursor[dst[i]], 1); eid[pos]=i; }
}

// ---------------- generic bf16 MFMA GEMM ----------------
__global__ __launch_bounds__(256) void k_gemm(const ushort_t* __restrict__ Ain, const ushort_t* __restrict__ Wg,
      int M, int N, int K, const float* __restrict__ bias, int mode,
      ushort_t* __restrict__ outb, float* __restrict__ outf, const float* __restrict__ addf){
  __shared__ __align__(16) ushort_t As[64*LDA];
  __shared__ __align__(16) ushort_t Bs[64*LDA];
  int tid = threadIdx.x;
  int m0 = blockIdx.x*64, n0 = blockIdx.y*64;
  int w = tid>>6, lane = tid&63, row16 = lane&15, quad = lane>>4;
  floatx4 acc[4];
  #pragma unroll
  for(int t=0;t<4;t++) acc[t]=(floatx4)(0.f);
  int nk = K>>6;
  for(int kc=0; kc<nk; kc++){
    #pragma unroll
    for(int i=0;i<2;i++){
      int lin = tid + i*256;
      int row = lin>>3, c8 = (lin&7)*8;
      uint4 va;
      int gm = m0+row;
      if(gm < M) va = *(const uint4*)&Ain[(size_t)gm*K + kc*64 + c8];
      else va = make_uint4(0,0,0,0);
      *(uint4*)&As[row*LDA + c8] = va;
      uint4 vb = *(const uint4*)&Wg[(size_t)(n0+row)*K + kc*64 + c8];
      *(uint4*)&Bs[row*LDA + c8] = vb;
    }
    __syncthreads();
    #pragma unroll
    for(int ks=0;ks<2;ks++){
      short8 a = *(const short8*)&As[(w*16+row16)*LDA + ks*32 + quad*8];
      #pragma unroll
      for(int t=0;t<4;t++){
        short8 b = *(const short8*)&Bs[(t*16+row16)*LDA + ks*32 + quad*8];
        acc[t] = __builtin_amdgcn_mfma_f32_16x16x32_bf16(a,b,acc[t],0,0,0);
      }
    }
    __syncthreads();
  }
  #pragma unroll
  for(int t=0;t<4;t++){
    int nn = n0 + t*16 + row16;
    #pragma unroll
    for(int r=0;r<4;r++){
      int m = m0 + w*16 + quad*4 + r;
      if(m>=M) continue;
      float v = acc[t][r];
      if(mode==1){ v += bias[nn]; v = v>0.f? v:0.f; outb[(size_t)m*N+nn]=f2bf(v); }
      else if(mode==2){ v += bias[nn] + addf[(size_t)m*N+nn]; outf[(size_t)m*N+nn]=v; }
      else { outb[(size_t)m*N+nn]=f2bf(v); }
    }
  }
}

// ---------------- fused per-edge message kernel (v2: LDS transpose epilogue) ----------------
// LDS map (47616 B total):
//   [0,36864)      We      256 x LDA bf16    (phase 1/MFMA)
//   [0,33792)      spk     64 x SPK_S uint   (phase 2/3, overlays We after MFMA)
//   [36864,46080)  el      64 x LDA bf16
//   [46080,46336)  dl[64]; [46336,46592) sl[64]
//   [46592,47104)  bfl[128] f32; [47104,47616) bsl[128] f32
__global__ __launch_bounds__(256) void k_edge_msg(const float* __restrict__ ea,
      const int* __restrict__ src_g, const int* __restrict__ dst_g,
      const ushort_t* __restrict__ Wedge, const ushort_t* __restrict__ Atab,
      const float* __restrict__ bf, const float* __restrict__ bs,
      ushort_t* __restrict__ msg){
  __shared__ __align__(16) char smem[47616];
  ushort_t* We  = (ushort_t*)smem;
  unsigned* spk = (unsigned*)smem;
  ushort_t* el  = (ushort_t*)(smem + 36864);
  int*      dl  = (int*)(smem + 46080);
  int*      sl  = (int*)(smem + 46336);
  float*    bfl = (float*)(smem + 46592);
  float*    bsl = (float*)(smem + 47104);

  int tid = threadIdx.x;
  int e0 = blockIdx.x*64;
  // stage Wedge [256,64] bf16 -> LDS
  {
    const uint4* s = (const uint4*)Wedge;
    #pragma unroll
    for(int i=0;i<8;i++){
      int idx = tid + i*256;
      int row = idx>>3, col = (idx&7)*8;
      *(uint4*)&We[row*LDA + col] = s[idx];
    }
  }
  // stage edge_attr tile [64,64] f32 -> bf16 LDS
  {
    int row = tid>>2, c0 = (tid&3)*16;
    const float4* p = (const float4*)&ea[(size_t)(e0+row)*64 + c0];
    float4 f0=p[0], f1=p[1], f2=p[2], f3=p[3];
    uint4 q0, q1;
    q0.x=pk2(f0.x,f0.y); q0.y=pk2(f0.z,f0.w); q0.z=pk2(f1.x,f1.y); q0.w=pk2(f1.z,f1.w);
    q1.x=pk2(f2.x,f2.y); q1.y=pk2(f2.z,f2.w); q1.z=pk2(f3.x,f3.y); q1.w=pk2(f3.z,f3.w);
    *(uint4*)&el[row*LDA + c0] = q0;
    *(uint4*)&el[row*LDA + c0 + 8] = q1;
  }
  if(tid<64){ dl[tid]=dst_g[e0+tid]; sl[tid]=src_g[e0+tid]; }
  if(tid>=128 && tid<256){ int t2=tid-128; bfl[t2]=bf[t2]; }
  if(tid<128){ bsl[tid]=bs[tid]; }
  __syncthreads();

  int w = tid>>6, lane = tid&63, row16 = lane&15, quad = lane>>4;
  floatx4 acc[16];
  #pragma unroll
  for(int t=0;t<16;t++) acc[t]=(floatx4)(0.f);
  #pragma unroll
  for(int ks=0;ks<2;ks++){
    short8 a = *(const short8*)&el[(w*16+row16)*LDA + ks*32 + quad*8];
    #pragma unroll
    for(int t=0;t<16;t++){
      short8 b = *(const short8*)&We[(t*16+row16)*LDA + ks*32 + quad*8];
      acc[t]=__builtin_amdgcn_mfma_f32_16x16x32_bf16(a,b,acc[t],0,0,0);
    }
  }
  __syncthreads();   // all We reads done before overlay writes

  // phase 2: acc -> LDS, packed (fv,sv) bf16 pair per channel, + bias
  #pragma unroll
  for(int t=0;t<8;t++){
    int c = t*16 + row16;
    float bfc = bfl[c], bsc = bsl[c];
    #pragma unroll
    for(int r=0;r<4;r++){
      int rl = w*16 + quad*4 + r;
      spk[rl*SPK_S + c] = pk2(acc[t][r] + bfc, acc[t+8][r] + bsc);
    }
  }
  __syncthreads();

  // phase 3: per lane: one edge x 8 contiguous channels; vector gathers + activation
  #pragma unroll
  for(int j=0;j<4;j++){
    int id  = j*256 + tid;
    int eli = id >> 4;
    int c0  = (id & 15) * 8;
    int d = dl[eli], s = sl[eli];
    const unsigned* base = &spk[eli*SPK_S + c0];
    uint4 q0 = *(const uint4*)(base);
    uint4 q1 = *(const uint4*)(base + 4);
    const ushort_t* Adp = Atab + (size_t)d*512;
    const ushort_t* Asp = Atab + (size_t)s*512;
    uint4 a0 = *(const uint4*)&Adp[c0];        // fv dst term, ch pairs
    uint4 a1 = *(const uint4*)&Asp[128+c0];    // fv src term
    uint4 a2 = *(const uint4*)&Adp[256+c0];    // sv dst term
    uint4 a3 = *(const uint4*)&Asp[384+c0];    // sv src term
    unsigned qs[8] = {q0.x,q0.y,q0.z,q0.w,q1.x,q1.y,q1.z,q1.w};
    unsigned A0[4] = {a0.x,a0.y,a0.z,a0.w};
    unsigned A1[4] = {a1.x,a1.y,a1.z,a1.w};
    unsigned A2[4] = {a2.x,a2.y,a2.z,a2.w};
    unsigned A3[4] = {a3.x,a3.y,a3.z,a3.w};
    unsigned outw[4];
    #pragma unroll
    for(int k=0;k<4;k++){
      float fv0 = bflo(qs[2*k])   + bflo(A0[k]) + bflo(A1[k]);
      float sv0 = bfhi(qs[2*k])   + bflo(A2[k]) + bflo(A3[k]);
      float fv1 = bflo(qs[2*k+1]) + bfhi(A0[k]) + bfhi(A1[k]);
      float sv1 = bfhi(qs[2*k+1]) + bfhi(A2[k]) + bfhi(A3[k]);
      float sig0 = 1.f/(1.f+__expf(-fv0));
      float sig1 = 1.f/(1.f+__expf(-fv1));
      float sp0  = fmaxf(sv0,0.f) + __logf(1.f+__expf(-fabsf(sv0)));
      float sp1  = fmaxf(sv1,0.f) + __logf(1.f+__expf(-fabsf(sv1)));
      outw[k] = pk2(sig0*sp0, sig1*sp1);
    }
    uint4 o4; o4.x=outw[0]; o4.y=outw[1]; o4.z=outw[2]; o4.w=outw[3];
    *(uint4*)&msg[(size_t)(e0+eli)*128 + c0] = o4;
  }
}

// ---------------- CSR aggregate ----------------
__global__ __launch_bounds__(256) void k_aggregate(const ushort_t* __restrict__ msg,
      const int* __restrict__ eid, const int* __restrict__ offs,
      float* __restrict__ xcur, ushort_t* __restrict__ xb){
  int v = blockIdx.x*4 + (threadIdx.x>>6);
  int lane = threadIdx.x & 63;
  int c0 = lane*2;
  float2 a = *(float2*)&xcur[(size_t)v*128 + c0];
  int b = offs[v], e_ = offs[v+1];
  for(int j=b;j<e_;j++){
    int e = eid[j];
    unsigned mm = *(const unsigned*)&msg[(size_t)e*128 + c0];
    a.x += bflo(mm);
    a.y += bfhi(mm);
  }
  *(float2*)&xcur[(size_t)v*128 + c0] = a;
  *(unsigned*)&xb[(size_t)v*128 + c0] = pk2(a.x, a.y);
}

// ---------------- pooling (batch is sorted: run-accumulate, few atomics) ----------------
__global__ __launch_bounds__(256) void k_pool(const float* __restrict__ xcur,
      const int* __restrict__ batch, float* __restrict__ pooled){
  int b0 = blockIdx.x * 128;
  int ch = threadIdx.x & 127;
  int half = threadIdx.x >> 7;
  int n0 = b0 + half*64;
  if(n0 >= NN) return;
  int n1 = n0 + 64; if(n1 > NN) n1 = NN;
  float sum = 0.f;
  int bid = batch[n0];
  for(int n=n0; n<n1; n++){
    int b = batch[n];
    if(b != bid){ atomicAdd(&pooled[(size_t)bid*128+ch], sum); sum=0.f; bid=b; }
    sum += xcur[(size_t)n*128 + ch];
  }
  atomicAdd(&pooled[(size_t)bid*128+ch], sum);
}

// ---------------- mlp2 + residual + head ----------------
__global__ __launch_bounds__(256) void k_final(const float* __restrict__ pooled,
   const float* __restrict__ W0, const float* __restrict__ b0,
   const float* __restrict__ W1, const float* __restrict__ b1,
   const float* __restrict__ Wp, const float* __restrict__ bp,
   const float* __restrict__ outW, const float* __restrict__ outB,
   float* __restrict__ out){
  __shared__ float p[128], h0[256], h1[256], red[256];
  int g = blockIdx.x, t = threadIdx.x;
  if(t<128) p[t]=pooled[(size_t)g*128+t];
  __syncthreads();
  {
    const float4* wr = (const float4*)&W0[(size_t)t*128];
    float s=0.f;
    #pragma unroll 8
    for(int k=0;k<32;k++){ float4 wv=wr[k]; s += wv.x*p[k*4]+wv.y*p[k*4+1]+wv.z*p[k*4+2]+wv.w*p[k*4+3]; }
    s += b0[t]; h0[t] = s>0.f? s:0.f;
  }
  __syncthreads();
  {
    const float4* wr = (const float4*)&W1[(size_t)t*256];
    float s=0.f;
    #pragma unroll 8
    for(int k=0;k<64;k++){ float4 wv=wr[k]; s += wv.x*h0[k*4]+wv.y*h0[k*4+1]+wv.z*h0[k*4+2]+wv.w*h0[k*4+3]; }
    s += b1[t]; h1[t] = s>0.f? s:0.f;
  }
  __syncthreads();
  float rt = 0.f;
  if(t<128){
    const float4* wr=(const float4*)&Wp[(size_t)t*256];
    float s=0.f;
    #pragma unroll 8
    for(int k=0;k<64;k++){ float4 wv=wr[k]; s += wv.x*h1[k*4]+wv.y*h1[k*4+1]+wv.z*h1[k*4+2]+wv.w*h1[k*4+3]; }
    s += bp[t] + p[t];
    rt = s * outW[t];
  }
  red[t]=rt; __syncthreads();
  for(int o=128;o>0;o>>=1){ if(t<o) red[t]+=red[t+o]; __syncthreads(); }
  if(t==0) out[g] = red[0] + outB[0];
}

extern "C" void kernel_launch(void* const* d_in, const int* in_sizes, int n_in,
                              void* d_out, int out_size, void* d_ws, size_t ws_size,
                              hipStream_t stream){
  const float* x    = (const float*)d_in[0];
  const int*   ei   = (const int*)d_in[1];
  const float* ea   = (const float*)d_in[2];
  const int*   batch= (const int*)d_in[3];
  const float* cWf  = (const float*)d_in[4];
  const float* cbf  = (const float*)d_in[5];
  const float* cWs  = (const float*)d_in[6];
  const float* cbs  = (const float*)d_in[7];
  const float* W0   = (const float*)d_in[8];
  const float* b0   = (const float*)d_in[9];
  const float* W1   = (const float*)d_in[10];
  const float* b1   = (const float*)d_in[11];
  const float* Wp   = (const float*)d_in[12];
  const float* bp   = (const float*)d_in[13];
  const float* m2W0 = (const float*)d_in[14];
  const float* m2b0 = (const float*)d_in[15];
  const float* m2W1 = (const float*)d_in[16];
  const float* m2b1 = (const float*)d_in[17];
  const float* m2Wp = (const float*)d_in[18];
  const float* m2bp = (const float*)d_in[19];
  const float* outW = (const float*)d_in[20];
  const float* outB = (const float*)d_in[21];

  const int* srcp = ei;
  const int* dstp = ei + NE;

  char* ws = (char*)d_ws;
  size_t off = 0;
  auto alloc = [&](size_t bytes)->char*{
    char* p = ws + off;
    off += (bytes + 255) & ~(size_t)255;
    return p;
  };
  float*    xcur  = (float*)   alloc((size_t)NN*DN*4);
  ushort_t* xb    = (ushort_t*)alloc((size_t)NN*DN*2);
  ushort_t* Atab  = (ushort_t*)alloc((size_t)NN*512*2);   // reused as h0/h1 for mlp1
  ushort_t* msg   = (ushort_t*)alloc((size_t)NE*128*2);
  ushort_t* Wnode = (ushort_t*)alloc((size_t)2*512*128*2);
  ushort_t* Wedge = (ushort_t*)alloc((size_t)2*256*64*2);
  ushort_t* W0b   = (ushort_t*)alloc((size_t)256*128*2);
  ushort_t* W1b   = (ushort_t*)alloc((size_t)256*256*2);
  ushort_t* Wpb   = (ushort_t*)alloc((size_t)128*256*2);
  int*      deg   = (int*)     alloc((size_t)NN*4);
  int*      offs  = (int*)     alloc((size_t)(NN+1)*4);
  int*      cursor= (int*)     alloc((size_t)NN*4);
  int*      eid   = (int*)     alloc((size_t)NE*4);
  int*      bsum  = (int*)     alloc(256*4);
  float*    pooled= (float*)   alloc((size_t)NG*DN*4);
  ushort_t* h0 = Atab;
  ushort_t* h1 = Atab + (size_t)NN*256;

  k_conv_node_w<<<(2*512*128+255)/256, 256, 0, stream>>>(cWf, cWs, Wnode);
  k_conv_edge_w<<<(2*256*64+255)/256, 256, 0, stream>>>(cWf, cWs, Wedge);
  k_f2bf<<<(256*128+255)/256, 256, 0, stream>>>(W0, W0b, 256*128);
  k_f2bf<<<(256*256+255)/256, 256, 0, stream>>>(W1, W1b, 256*256);
  k_f2bf<<<(128*256+255)/256, 256, 0, stream>>>(Wp, Wpb, 128*256);
  k_init_x<<<(NN*DN+255)/256, 256, 0, stream>>>(x, xcur, xb);

  int nb = (NN+255)/256;
  k_zero_u32<<<(NN+255)/256, 256, 0, stream>>>((unsigned*)deg, NN);
  k_hist<<<(NE+255)/256, 256, 0, stream>>>(dstp, deg);
  k_blocksum<<<nb, 256, 0, stream>>>(deg, bsum, NN);
  k_scan_bsum<<<1, 256, 0, stream>>>(bsum, nb, offs, NN);
  k_scanscatter<<<nb, 256, 0, stream>>>(deg, bsum, offs, cursor, NN);
  k_scatter<<<(NE+255)/256, 256, 0, stream>>>(dstp, cursor, eid);

  for(int l=0;l<2;l++){
    dim3 ga((NN+63)/64, 512/64);
    k_gemm<<<ga, 256, 0, stream>>>(xb, Wnode + (size_t)l*512*128, NN, 512, 128,
                                   nullptr, 0, Atab, nullptr, nullptr);
    k_edge_msg<<<NE/64, 256, 0, stream>>>(ea, srcp, dstp, Wedge + (size_t)l*256*64,
                                          Atab, cbf + l*128, cbs + l*128, msg);
    k_aggregate<<<NN/4, 256, 0, stream>>>(msg, eid, offs, xcur, xb);
  }

  {
    dim3 g0((NN+63)/64, 256/64);
    k_gemm<<<g0, 256, 0, stream>>>(xb, W0b, NN, 256, 128, b0, 1, h0, nullptr, nullptr);
    dim3 g1((NN+63)/64, 256/64);
    k_gemm<<<g1, 256, 0, stream>>>(h0, W1b, NN, 256, 256, b1, 1, h1, nullptr, nullptr);
    dim3 g2((NN+63)/64, 128/64);
    k_gemm<<<g2, 256, 0, stream>>>(h1, Wpb, NN, 128, 256, bp, 2, nullptr, xcur, xcur);
  }

  k_zero_u32<<<(NG*DN+255)/256, 256, 0, stream>>>((unsigned*)pooled, NG*DN);
  k_pool<<<(NN+127)/128, 256, 0, stream>>>(xcur, batch, pooled);

  k_final<<<NG, 256, 0, stream>>>(pooled, m2W0, m2b0, m2W1, m2b1, m2Wp, m2bp,
                                  outW, outB, (float*)d_out);
  (void)in_sizes; (void)n_in; (void)out_size; (void)ws_size;
}

// Round 3
// 1015.423 us; speedup vs baseline: 1.7319x; 1.2056x over previous
//
#include <hip/hip_runtime.h>
#include <stdint.h>

#define NN 50000
#define NE 800000
#define DN 128
#define DE 64
#define NG 512
#define HD 256
#define LDA 72    // padded LDS stride (elems) for 64-elem bf16 rows (144B = 9*16B, conflict-free-ish)
#define SPK_S 132 // uint stride for packed fv/sv rows (528B, 16B-aligned)

typedef unsigned short ushort_t;
typedef __attribute__((ext_vector_type(8))) short short8;
typedef __attribute__((ext_vector_type(4))) float floatx4;

__device__ __forceinline__ float bflo(unsigned u){ unsigned v=u<<16; float f; __builtin_memcpy(&f,&v,4); return f; }
__device__ __forceinline__ float bfhi(unsigned u){ unsigned v=u&0xffff0000u; float f; __builtin_memcpy(&f,&v,4); return f; }
__device__ __forceinline__ ushort_t f2bf(float f){ unsigned u; __builtin_memcpy(&u,&f,4); u += 0x7FFFu + ((u>>16)&1u); return (ushort_t)(u>>16); }
__device__ __forceinline__ unsigned cvtpk(float a, float b){
#if __has_builtin(__builtin_amdgcn_cvt_pk_bf16_f32)
  auto r = __builtin_amdgcn_cvt_pk_bf16_f32(a,b);
  unsigned u; __builtin_memcpy(&u,&r,4); return u;
#else
  return (unsigned)f2bf(a) | ((unsigned)f2bf(b)<<16);
#endif
}

// sigmoid(fv) * softplus(sv), via native exp2/log2/rcp
__device__ __forceinline__ float actv(float fv, float sv){
  const float L2E = 1.44269504f, LN2 = 0.69314718f;
  float ef  = __builtin_amdgcn_exp2f(-L2E*fv);
  float sig = __builtin_amdgcn_rcpf(1.f+ef);
  float t   = __builtin_amdgcn_exp2f(-L2E*fabsf(sv));
  float sp  = fmaxf(sv,0.f) + LN2*__builtin_amdgcn_logf(1.f+t);
  return sig*sp;
}

// ---------------- fused prep: all weight conversions + combined bias512 ----------------
// ranges: [0,131072) Wnode | [131072,163840) Wedge | [163840,196608) W0b
//         [196608,262144) W1b | [262144,294912) Wpb | [294912,295936) bias512
__global__ void k_prep(const float* __restrict__ Wf, const float* __restrict__ Ws,
                       const float* __restrict__ W0, const float* __restrict__ W1, const float* __restrict__ Wp,
                       const float* __restrict__ cbf, const float* __restrict__ cbs,
                       ushort_t* Wnode, ushort_t* Wedge, ushort_t* W0b, ushort_t* W1b, ushort_t* Wpb,
                       float* bias512){
  int i = blockIdx.x*256 + threadIdx.x;
  if(i < 131072){
    int l = i >> 16, r = i & 65535;
    int n = r >> 7, k = r & 127;
    const float* W = (n<256)? Wf : Ws;
    int nn = n & 127;
    int koff = ((n>>7)&1) ? 128+k : k;
    Wnode[i] = f2bf(W[(size_t)l*128*320 + (size_t)nn*320 + koff]);
  } else if(i < 163840){
    int j = i - 131072;
    int l = j >> 14, r = j & 16383;
    int n = r >> 6, k = r & 63;
    const float* W = (n<128)? Wf : Ws;
    int nn = n & 127;
    Wedge[j] = f2bf(W[(size_t)l*128*320 + (size_t)nn*320 + 256 + k]);
  } else if(i < 196608){
    int j = i - 163840; W0b[j] = f2bf(W0[j]);
  } else if(i < 262144){
    int j = i - 196608; W1b[j] = f2bf(W1[j]);
  } else if(i < 294912){
    int j = i - 262144; Wpb[j] = f2bf(Wp[j]);
  } else if(i < 295936){
    int j = i - 294912;
    int l = j >> 9, c = j & 511;
    float v = 0.f;
    if(c < 128) v = cbf[l*128 + c];
    else if(c >= 256 && c < 384) v = cbs[l*128 + (c-256)];
    bias512[j] = v;
  }
}

__global__ void k_init_x(const float* x, float* xcur, ushort_t* xb){
  int i = blockIdx.x*256 + threadIdx.x;
  if(i < NN*DN){ float v = x[i]; xcur[i]=v; xb[i]=f2bf(v); }
}

__global__ void k_zero_u32(unsigned* p, int n){
  int i = blockIdx.x*256 + threadIdx.x;
  if(i<n) p[i]=0u;
}

// ---------------- CSR build ----------------
__global__ void k_hist(const int* dst, int* deg){
  int i = blockIdx.x*256 + threadIdx.x;
  if(i<NE) atomicAdd(&deg[dst[i]], 1);
}

__global__ void k_blocksum(const int* deg, int* bsum, int n){
  __shared__ int s[256];
  int t = threadIdx.x, i = blockIdx.x*256 + t;
  s[t] = (i<n)? deg[i] : 0;
  __syncthreads();
  for(int o=128;o>0;o>>=1){ if(t<o) s[t]+=s[t+o]; __syncthreads(); }
  if(t==0) bsum[blockIdx.x]=s[0];
}

__global__ void k_scan_bsum(int* bsum, int nb, int* offs, int nnodes){
  __shared__ int s[2][256];
  int t = threadIdx.x;
  int v = (t<nb)? bsum[t] : 0;
  s[0][t]=v; __syncthreads();
  int cur=0;
  for(int o=1;o<256;o<<=1){
    int nx=cur^1;
    s[nx][t] = s[cur][t] + ((t>=o)? s[cur][t-o] : 0);
    cur=nx; __syncthreads();
  }
  if(t<nb) bsum[t] = s[cur][t] - v;
  if(t==255) offs[nnodes] = s[cur][255];
}

__global__ void k_scanscatter(const int* deg, const int* bsum, int* offs, int* cursor, int n){
  __shared__ int s[2][256];
  int t=threadIdx.x, i=blockIdx.x*256+t;
  int v=(i<n)? deg[i] : 0;
  s[0][t]=v; __syncthreads();
  int cur=0;
  for(int o=1;o<256;o<<=1){
    int nx=cur^1;
    s[nx][t] = s[cur][t] + ((t>=o)? s[cur][t-o] : 0);
    cur=nx; __syncthreads();
  }
  if(i<n){ int ex = s[cur][t]-v + bsum[blockIdx.x]; offs[i]=ex; cursor[i]=ex; }
}

__global__ void k_scatter(const int* dst, int* cursor, int* csr_pos){
  int i = blockIdx.x*256 + threadIdx.x;
  if(i<NE){ int pos = atomicAdd(&cursor[dst[i]], 1); csr_pos[i]=pos; }
}

// ---------------- generic bf16 MFMA GEMM ----------------
// mode 0: (+bias if given) store bf16; mode 1: +bias, relu, bf16; mode 2: +bias +addf, f32
__global__ __launch_bounds__(256) void k_gemm(const ushort_t* __restrict__ Ain, const ushort_t* __restrict__ Wg,
      int M, int N, int K, const float* __restrict__ bias, int mode,
      ushort_t* __restrict__ outb, float* __restrict__ outf, const float* __restrict__ addf){
  __shared__ __align__(16) ushort_t As[64*LDA];
  __shared__ __align__(16) ushort_t Bs[64*LDA];
  int tid = threadIdx.x;
  int m0 = blockIdx.x*64, n0 = blockIdx.y*64;
  int w = tid>>6, lane = tid&63, row16 = lane&15, quad = lane>>4;
  floatx4 acc[4];
  #pragma unroll
  for(int t=0;t<4;t++) acc[t]=(floatx4)(0.f);
  int nk = K>>6;
  for(int kc=0; kc<nk; kc++){
    #pragma unroll
    for(int i=0;i<2;i++){
      int lin = tid + i*256;
      int row = lin>>3, c8 = (lin&7)*8;
      uint4 va;
      int gm = m0+row;
      if(gm < M) va = *(const uint4*)&Ain[(size_t)gm*K + kc*64 + c8];
      else va = make_uint4(0,0,0,0);
      *(uint4*)&As[row*LDA + c8] = va;
      uint4 vb = *(const uint4*)&Wg[(size_t)(n0+row)*K + kc*64 + c8];
      *(uint4*)&Bs[row*LDA + c8] = vb;
    }
    __syncthreads();
    #pragma unroll
    for(int ks=0;ks<2;ks++){
      short8 a = *(const short8*)&As[(w*16+row16)*LDA + ks*32 + quad*8];
      #pragma unroll
      for(int t=0;t<4;t++){
        short8 b = *(const short8*)&Bs[(t*16+row16)*LDA + ks*32 + quad*8];
        acc[t] = __builtin_amdgcn_mfma_f32_16x16x32_bf16(a,b,acc[t],0,0,0);
      }
    }
    __syncthreads();
  }
  #pragma unroll
  for(int t=0;t<4;t++){
    int nn = n0 + t*16 + row16;
    #pragma unroll
    for(int r=0;r<4;r++){
      int m = m0 + w*16 + quad*4 + r;
      if(m>=M) continue;
      float v = acc[t][r];
      if(bias) v += bias[nn];
      if(mode==1){ v = v>0.f? v:0.f; outb[(size_t)m*N+nn]=f2bf(v); }
      else if(mode==2){ v += addf[(size_t)m*N+nn]; outf[(size_t)m*N+nn]=v; }
      else { outb[(size_t)m*N+nn]=f2bf(v); }
    }
  }
}

// ---------------- fused per-edge message kernel (v3: CSR-ordered write, hw cvt_pk) ----------------
// LDS: [0,36864) We (MFMA) / spk 64xSPK_S uint (overlay after MFMA)
//      [36864,46080) el ; [46080,46336) dl ; [46336,46592) sl ; [46592,46848) cp
__global__ __launch_bounds__(256) void k_edge_msg(const float* __restrict__ ea,
      const int* __restrict__ src_g, const int* __restrict__ dst_g,
      const int* __restrict__ csr_pos,
      const ushort_t* __restrict__ Wedge, const ushort_t* __restrict__ Atab,
      ushort_t* __restrict__ msg){
  __shared__ __align__(16) char smem[46848];
  ushort_t* We  = (ushort_t*)smem;
  unsigned* spk = (unsigned*)smem;
  ushort_t* el  = (ushort_t*)(smem + 36864);
  int*      dl  = (int*)(smem + 46080);
  int*      sl  = (int*)(smem + 46336);
  int*      cp  = (int*)(smem + 46592);

  int tid = threadIdx.x;
  int e0 = blockIdx.x*64;
  {
    const uint4* s = (const uint4*)Wedge;
    #pragma unroll
    for(int i=0;i<8;i++){
      int idx = tid + i*256;
      int row = idx>>3, col = (idx&7)*8;
      *(uint4*)&We[row*LDA + col] = s[idx];
    }
  }
  {
    int row = tid>>2, c0 = (tid&3)*16;
    const float4* p = (const float4*)&ea[(size_t)(e0+row)*64 + c0];
    float4 f0=p[0], f1=p[1], f2=p[2], f3=p[3];
    uint4 q0, q1;
    q0.x=cvtpk(f0.x,f0.y); q0.y=cvtpk(f0.z,f0.w); q0.z=cvtpk(f1.x,f1.y); q0.w=cvtpk(f1.z,f1.w);
    q1.x=cvtpk(f2.x,f2.y); q1.y=cvtpk(f2.z,f2.w); q1.z=cvtpk(f3.x,f3.y); q1.w=cvtpk(f3.z,f3.w);
    *(uint4*)&el[row*LDA + c0] = q0;
    *(uint4*)&el[row*LDA + c0 + 8] = q1;
  }
  if(tid<64){ dl[tid]=dst_g[e0+tid]; sl[tid]=src_g[e0+tid]; }
  else if(tid>=64 && tid<128){ cp[tid-64]=csr_pos[e0+tid-64]; }
  __syncthreads();

  int w = tid>>6, lane = tid&63, row16 = lane&15, quad = lane>>4;
  floatx4 acc[16];
  #pragma unroll
  for(int t=0;t<16;t++) acc[t]=(floatx4)(0.f);
  #pragma unroll
  for(int ks=0;ks<2;ks++){
    short8 a = *(const short8*)&el[(w*16+row16)*LDA + ks*32 + quad*8];
    #pragma unroll
    for(int t=0;t<16;t++){
      short8 b = *(const short8*)&We[(t*16+row16)*LDA + ks*32 + quad*8];
      acc[t]=__builtin_amdgcn_mfma_f32_16x16x32_bf16(a,b,acc[t],0,0,0);
    }
  }
  __syncthreads();   // We reads done before overlay

  // phase 2: acc -> LDS packed (fv,sv) per channel (bias pre-folded into Atab via GEMM)
  #pragma unroll
  for(int t=0;t<8;t++){
    int c = t*16 + row16;
    #pragma unroll
    for(int r=0;r<4;r++){
      int rl = w*16 + quad*4 + r;
      spk[rl*SPK_S + c] = cvtpk(acc[t][r], acc[t+8][r]);
    }
  }
  __syncthreads();

  // phase 3: lane = one edge x 8 contiguous channels
  #pragma unroll
  for(int j=0;j<4;j++){
    int id  = j*256 + tid;
    int eli = id >> 4;
    int c0  = (id & 15) * 8;
    int d = dl[eli], s = sl[eli], mrow = cp[eli];
    const unsigned* base = &spk[eli*SPK_S + c0];
    uint4 q0 = *(const uint4*)(base);
    uint4 q1 = *(const uint4*)(base + 4);
    const ushort_t* Adp = Atab + (size_t)d*512;
    const ushort_t* Asp = Atab + (size_t)s*512;
    uint4 a0 = *(const uint4*)&Adp[c0];
    uint4 a1 = *(const uint4*)&Asp[128+c0];
    uint4 a2 = *(const uint4*)&Adp[256+c0];
    uint4 a3 = *(const uint4*)&Asp[384+c0];
    unsigned qs[8] = {q0.x,q0.y,q0.z,q0.w,q1.x,q1.y,q1.z,q1.w};
    unsigned A0[4] = {a0.x,a0.y,a0.z,a0.w};
    unsigned A1[4] = {a1.x,a1.y,a1.z,a1.w};
    unsigned A2[4] = {a2.x,a2.y,a2.z,a2.w};
    unsigned A3[4] = {a3.x,a3.y,a3.z,a3.w};
    unsigned outw[4];
    #pragma unroll
    for(int k=0;k<4;k++){
      float fv0 = bflo(qs[2*k])   + bflo(A0[k]) + bflo(A1[k]);
      float sv0 = bfhi(qs[2*k])   + bflo(A2[k]) + bflo(A3[k]);
      float fv1 = bflo(qs[2*k+1]) + bfhi(A0[k]) + bfhi(A1[k]);
      float sv1 = bfhi(qs[2*k+1]) + bfhi(A2[k]) + bfhi(A3[k]);
      outw[k] = cvtpk(actv(fv0,sv0), actv(fv1,sv1));
    }
    uint4 o4; o4.x=outw[0]; o4.y=outw[1]; o4.z=outw[2]; o4.w=outw[3];
    *(uint4*)&msg[(size_t)mrow*128 + c0] = o4;
  }
}

// ---------------- streaming CSR aggregate: msg rows for node v are contiguous ----------------
__global__ __launch_bounds__(256) void k_aggregate(const ushort_t* __restrict__ msg,
      const int* __restrict__ offs, float* __restrict__ xcur, ushort_t* __restrict__ xb){
  int v = blockIdx.x*4 + (threadIdx.x>>6);
  int lane = threadIdx.x & 63;
  int rslot = lane>>4;
  int c0 = (lane&15)*8;
  int b = offs[v], e = offs[v+1];
  float acc[8];
  #pragma unroll
  for(int k=0;k<8;k++) acc[k]=0.f;
  for(int r=b+rslot; r<e; r+=4){
    uint4 m = *(const uint4*)&msg[(size_t)r*128 + c0];
    acc[0]+=bflo(m.x); acc[1]+=bfhi(m.x);
    acc[2]+=bflo(m.y); acc[3]+=bfhi(m.y);
    acc[4]+=bflo(m.z); acc[5]+=bfhi(m.z);
    acc[6]+=bflo(m.w); acc[7]+=bfhi(m.w);
  }
  #pragma unroll
  for(int k=0;k<8;k++){
    acc[k] += __shfl_xor(acc[k],16);
    acc[k] += __shfl_xor(acc[k],32);
  }
  if(rslot==0){
    float4 x0 = *(float4*)&xcur[(size_t)v*128+c0];
    float4 x1 = *(float4*)&xcur[(size_t)v*128+c0+4];
    x0.x+=acc[0]; x0.y+=acc[1]; x0.z+=acc[2]; x0.w+=acc[3];
    x1.x+=acc[4]; x1.y+=acc[5]; x1.z+=acc[6]; x1.w+=acc[7];
    *(float4*)&xcur[(size_t)v*128+c0]=x0;
    *(float4*)&xcur[(size_t)v*128+c0+4]=x1;
    uint4 o; o.x=cvtpk(x0.x,x0.y); o.y=cvtpk(x0.z,x0.w); o.z=cvtpk(x1.x,x1.y); o.w=cvtpk(x1.z,x1.w);
    *(uint4*)&xb[(size_t)v*128+c0]=o;
  }
}

// ---------------- pooling (sorted batch: run-accumulate) ----------------
__global__ __launch_bounds__(256) void k_pool(const float* __restrict__ xcur,
      const int* __restrict__ batch, float* __restrict__ pooled){
  int b0 = blockIdx.x * 128;
  int ch = threadIdx.x & 127;
  int half = threadIdx.x >> 7;
  int n0 = b0 + half*64;
  if(n0 >= NN) return;
  int n1 = n0 + 64; if(n1 > NN) n1 = NN;
  float sum = 0.f;
  int bid = batch[n0];
  for(int n=n0; n<n1; n++){
    int b = batch[n];
    if(b != bid){ atomicAdd(&pooled[(size_t)bid*128+ch], sum); sum=0.f; bid=b; }
    sum += xcur[(size_t)n*128 + ch];
  }
  atomicAdd(&pooled[(size_t)bid*128+ch], sum);
}

// ---------------- mlp2 + residual + head ----------------
__global__ __launch_bounds__(256) void k_final(const float* __restrict__ pooled,
   const float* __restrict__ W0, const float* __restrict__ b0,
   const float* __restrict__ W1, const float* __restrict__ b1,
   const float* __restrict__ Wp, const float* __restrict__ bp,
   const float* __restrict__ outW, const float* __restrict__ outB,
   float* __restrict__ out){
  __shared__ float p[128], h0[256], h1[256], red[256];
  int g = blockIdx.x, t = threadIdx.x;
  if(t<128) p[t]=pooled[(size_t)g*128+t];
  __syncthreads();
  {
    const float4* wr = (const float4*)&W0[(size_t)t*128];
    float s=0.f;
    #pragma unroll 8
    for(int k=0;k<32;k++){ float4 wv=wr[k]; s += wv.x*p[k*4]+wv.y*p[k*4+1]+wv.z*p[k*4+2]+wv.w*p[k*4+3]; }
    s += b0[t]; h0[t] = s>0.f? s:0.f;
  }
  __syncthreads();
  {
    const float4* wr = (const float4*)&W1[(size_t)t*256];
    float s=0.f;
    #pragma unroll 8
    for(int k=0;k<64;k++){ float4 wv=wr[k]; s += wv.x*h0[k*4]+wv.y*h0[k*4+1]+wv.z*h0[k*4+2]+wv.w*h0[k*4+3]; }
    s += b1[t]; h1[t] = s>0.f? s:0.f;
  }
  __syncthreads();
  float rt = 0.f;
  if(t<128){
    const float4* wr=(const float4*)&Wp[(size_t)t*256];
    float s=0.f;
    #pragma unroll 8
    for(int k=0;k<64;k++){ float4 wv=wr[k]; s += wv.x*h1[k*4]+wv.y*h1[k*4+1]+wv.z*h1[k*4+2]+wv.w*h1[k*4+3]; }
    s += bp[t] + p[t];
    rt = s * outW[t];
  }
  red[t]=rt; __syncthreads();
  for(int o=128;o>0;o>>=1){ if(t<o) red[t]+=red[t+o]; __syncthreads(); }
  if(t==0) out[g] = red[0] + outB[0];
}

extern "C" void kernel_launch(void* const* d_in, const int* in_sizes, int n_in,
                              void* d_out, int out_size, void* d_ws, size_t ws_size,
                              hipStream_t stream){
  const float* x    = (const float*)d_in[0];
  const int*   ei   = (const int*)d_in[1];
  const float* ea   = (const float*)d_in[2];
  const int*   batch= (const int*)d_in[3];
  const float* cWf  = (const float*)d_in[4];
  const float* cbf  = (const float*)d_in[5];
  const float* cWs  = (const float*)d_in[6];
  const float* cbs  = (const float*)d_in[7];
  const float* W0   = (const float*)d_in[8];
  const float* b0   = (const float*)d_in[9];
  const float* W1   = (const float*)d_in[10];
  const float* b1   = (const float*)d_in[11];
  const float* Wp   = (const float*)d_in[12];
  const float* bp   = (const float*)d_in[13];
  const float* m2W0 = (const float*)d_in[14];
  const float* m2b0 = (const float*)d_in[15];
  const float* m2W1 = (const float*)d_in[16];
  const float* m2b1 = (const float*)d_in[17];
  const float* m2Wp = (const float*)d_in[18];
  const float* m2bp = (const float*)d_in[19];
  const float* outW = (const float*)d_in[20];
  const float* outB = (const float*)d_in[21];

  const int* srcp = ei;
  const int* dstp = ei + NE;

  char* ws = (char*)d_ws;
  size_t off = 0;
  auto alloc = [&](size_t bytes)->char*{
    char* p = ws + off;
    off += (bytes + 255) & ~(size_t)255;
    return p;
  };
  float*    xcur   = (float*)   alloc((size_t)NN*DN*4);
  ushort_t* xb     = (ushort_t*)alloc((size_t)NN*DN*2);
  ushort_t* Atab   = (ushort_t*)alloc((size_t)NN*512*2);   // reused as h0/h1 for mlp1
  ushort_t* msg    = (ushort_t*)alloc((size_t)NE*128*2);
  ushort_t* Wnode  = (ushort_t*)alloc((size_t)2*512*128*2);
  ushort_t* Wedge  = (ushort_t*)alloc((size_t)2*256*64*2);
  ushort_t* W0b    = (ushort_t*)alloc((size_t)256*128*2);
  ushort_t* W1b    = (ushort_t*)alloc((size_t)256*256*2);
  ushort_t* Wpb    = (ushort_t*)alloc((size_t)128*256*2);
  float*    bias512= (float*)   alloc((size_t)2*512*4);
  int*      deg    = (int*)     alloc((size_t)NN*4);
  int*      offs   = (int*)     alloc((size_t)(NN+1)*4);
  int*      cursor = (int*)     alloc((size_t)NN*4);
  int*      csr_pos= (int*)     alloc((size_t)NE*4);
  int*      bsum   = (int*)     alloc(256*4);
  float*    pooled = (float*)   alloc((size_t)NG*DN*4);
  ushort_t* h0 = Atab;
  ushort_t* h1 = Atab + (size_t)NN*256;

  k_prep<<<1156, 256, 0, stream>>>(cWf, cWs, W0, W1, Wp, cbf, cbs,
                                   Wnode, Wedge, W0b, W1b, Wpb, bias512);
  k_init_x<<<(NN*DN+255)/256, 256, 0, stream>>>(x, xcur, xb);

  int nb = (NN+255)/256;
  k_zero_u32<<<(NN+255)/256, 256, 0, stream>>>((unsigned*)deg, NN);
  k_hist<<<(NE+255)/256, 256, 0, stream>>>(dstp, deg);
  k_blocksum<<<nb, 256, 0, stream>>>(deg, bsum, NN);
  k_scan_bsum<<<1, 256, 0, stream>>>(bsum, nb, offs, NN);
  k_scanscatter<<<nb, 256, 0, stream>>>(deg, bsum, offs, cursor, NN);
  k_scatter<<<(NE+255)/256, 256, 0, stream>>>(dstp, cursor, csr_pos);

  for(int l=0;l<2;l++){
    dim3 ga((NN+63)/64, 512/64);
    k_gemm<<<ga, 256, 0, stream>>>(xb, Wnode + (size_t)l*512*128, NN, 512, 128,
                                   bias512 + l*512, 0, Atab, nullptr, nullptr);
    k_edge_msg<<<NE/64, 256, 0, stream>>>(ea, srcp, dstp, csr_pos,
                                          Wedge + (size_t)l*256*64, Atab, msg);
    k_aggregate<<<NN/4, 256, 0, stream>>>(msg, offs, xcur, xb);
  }

  {
    dim3 g0((NN+63)/64, 256/64);
    k_gemm<<<g0, 256, 0, stream>>>(xb, W0b, NN, 256, 128, b0, 1, h0, nullptr, nullptr);
    dim3 g1((NN+63)/64, 256/64);
    k_gemm<<<g1, 256, 0, stream>>>(h0, W1b, NN, 256, 256, b1, 1, h1, nullptr, nullptr);
    dim3 g2((NN+63)/64, 128/64);
    k_gemm<<<g2, 256, 0, stream>>>(h1, Wpb, NN, 128, 256, bp, 2, nullptr, xcur, xcur);
  }

  k_zero_u32<<<(NG*DN+255)/256, 256, 0, stream>>>((unsigned*)pooled, NG*DN);
  k_pool<<<(NN+127)/128, 256, 0, stream>>>(xcur, batch, pooled);

  k_final<<<NG, 256, 0, stream>>>(pooled, m2W0, m2b0, m2W1, m2b1, m2Wp, m2bp,
                                  outW, outB, (float*)d_out);
  (void)in_sizes; (void)n_in; (void)out_size; (void)ws_size;
}